// Round 7
// baseline (254.257 us; speedup 1.0000x reference)
//
#include <hip/hip_runtime.h>
#include <math.h>

// DeepHit loss, MI355X. R=2 risks, B=8192, T=64 bins.
// Ints/bools delivered as int32 (verified R2/R4/R5: absmax 0).
//
// SINGLE persistent kernel (grid 256 x 1024, co-resident: 16 waves/block,
// capacity 2 blocks/CU) with 5 device-scope grid barriers:
//   P0 hist (blocks 0..7, LDS hist -> global merge)
//   P1 prefix (block 0, wave 0: 64-lane scans)
//   P2 counting-sort scatter (blocks 0..7)
//   P3 cum tiles: 512 tasks (event tiles: scan -> LDS -> coalesced
//      transposed cumTs store + likelihood; censored tiles: masked row-sum
//      -> aCens). 16 waves x 4 rows each (R5 was 4 waves x 16 rows at
//      2 waves/SIMD -> dependent-latency-bound ~16 us).
//   P4 rank: task b = (r, t, censored-half). Events of bin-prefix [0,ne)
//      in registers (4/thread), loop over half the bin's censored with
//      wave-uniform scalar a.
//   P5 final (block 0, wave 0).
// Barrier/accum state zeroed by hipMemsetAsync each call (graph-safe).
//
// R6: GPUAcquisitionTimeout (infra) — identical kernel resubmitted.

namespace {
constexpr int R  = 2;
constexpr int Bn = 8192;
constexpr int Tn = 64;
constexpr int NB = 256;
constexpr int NT = 1024;
constexpr float INV_SIGMA = 10.0f;   // 1/0.1
constexpr float EPS       = 1e-8f;
}

// ws layout (int32 offsets):
// 0    float llsumArr[64]   (zeroed)
// 64   int   cntArr[64]     (zeroed)
// 128  float rlsumArr[64]   (zeroed)
// 192  int   bar[2]         (zeroed: counter, generation)
// 208  int   binE[64]       (zeroed)
// 272  int   binC[64]       (zeroed)
// 336  int   limE[64]
// 400  int   cbaseA[64]
// 464  int   ncensA[64]
// 528  int   scatE[64]
// 592  int   scatC[64]
// 1024 int   esort[8192]
// 9216 int   csort[8192]
// 17408 float aCens[2*8192]
// 33792 float cumTs[2*64*8192]   (4 MB)

__device__ __forceinline__ void gridbar(int* bar, int want) {
    __syncthreads();
    if (threadIdx.x == 0) {
        __threadfence();   // agent-scope release of our prior writes
        int t = __hip_atomic_fetch_add(&bar[0], 1, __ATOMIC_ACQ_REL,
                                       __HIP_MEMORY_SCOPE_AGENT);
        if (t == NB - 1) {
            __hip_atomic_store(&bar[0], 0, __ATOMIC_RELAXED,
                               __HIP_MEMORY_SCOPE_AGENT);
            __hip_atomic_fetch_add(&bar[1], 1, __ATOMIC_ACQ_REL,
                                   __HIP_MEMORY_SCOPE_AGENT);
        } else {
            while (__hip_atomic_load(&bar[1], __ATOMIC_ACQUIRE,
                                     __HIP_MEMORY_SCOPE_AGENT) < want) {
                __builtin_amdgcn_s_sleep(2);
            }
        }
        __threadfence();   // agent-scope acquire for subsequent normal loads
    }
    __syncthreads();
}

__global__ void __launch_bounds__(NT)
k_fused(const float* __restrict__ risk, const int* __restrict__ tb,
        const int* __restrict__ rind, const int* __restrict__ ev,
        float* __restrict__ out, int* __restrict__ wsI) {
    float* llsumArr = (float*)(wsI + 0);
    int*   cntArr   = wsI + 64;
    float* rlsumArr = (float*)(wsI + 128);
    int*   bar      = wsI + 192;
    int*   binE     = wsI + 208;
    int*   binC     = wsI + 272;
    int*   limE     = wsI + 336;
    int*   cbaseA   = wsI + 400;
    int*   ncensA   = wsI + 464;
    int*   scatE    = wsI + 528;
    int*   scatC    = wsI + 592;
    int*   esort    = wsI + 1024;
    int*   csort    = wsI + 9216;
    float* aCens    = (float*)(wsI + 17408);
    float* cumTs    = (float*)(wsI + 33792);

    const int b    = blockIdx.x;
    const int tid  = threadIdx.x;
    const int lane = tid & 63;
    const int w    = tid >> 6;

    __shared__ float S[Tn][Tn + 1];
    __shared__ int idxS[Tn], tbS[Tn];
    __shared__ int hE[Tn], hC[Tn];

    // ---- P0: histogram ----
    if (b < 8) {
        if (tid < Tn) { hE[tid] = 0; hC[tid] = 0; }
        __syncthreads();
        int j = b * 1024 + tid;
        int t = tb[j];
        if (ev[j]) atomicAdd(&hE[t], 1);
        else       atomicAdd(&hC[t], 1);
        __syncthreads();
        if (tid < Tn) {
            if (hE[tid]) atomicAdd(&binE[tid], hE[tid]);
            if (hC[tid]) atomicAdd(&binC[tid], hC[tid]);
        }
    }
    gridbar(bar, 1);

    // ---- P1: prefix sums (block 0, wave 0) ----
    if (b == 0 && tid < 64) {
        int eC = binE[tid], cC = binC[tid];
        int se = eC, sc = cC;
#pragma unroll
        for (int o = 1; o < 64; o <<= 1) {
            int ue = __shfl_up(se, o, 64);
            int uc = __shfl_up(sc, o, 64);
            if (lane >= o) { se += ue; sc += uc; }
        }
        limE[tid]   = se;
        scatE[tid]  = se - eC;
        cbaseA[tid] = sc - cC;
        scatC[tid]  = sc - cC;
        ncensA[tid] = cC;
    }
    gridbar(bar, 2);

    // ---- P2: counting-sort scatter ----
    if (b < 8) {
        int j = b * 1024 + tid;
        int t = tb[j];
        if (ev[j]) { int p = atomicAdd(&scatE[t], 1); esort[p] = j; }
        else       { int p = atomicAdd(&scatC[t], 1); csort[p] = j; }
    }
    gridbar(bar, 3);

    // ---- P3: cum tiles (512 tasks; every block does c = b, then b+256) ----
    int nE = limE[Tn - 1];
    int nC = Bn - nE;
    for (int c = b; c < 512; c += NB) {
        bool isEvent = (c < 256);
        int r  = (c >> 7) & 1;
        int k0 = (c & 127) * 64;
        int tot = isEvent ? nE : nC;
        if (k0 < tot) {                       // block-uniform condition
            int cnt = min(64, tot - k0);
            if (tid < cnt) {
                int i = isEvent ? esort[k0 + tid] : csort[k0 + tid];
                idxS[tid] = i;
                tbS[tid]  = tb[i];
            }
            __syncthreads();
            if (isEvent) {
#pragma unroll
                for (int s = 0; s < 4; ++s) {
                    int ls = s * 16 + w;      // wave-uniform
                    if (ls < cnt) {
                        int i = idxS[ls];
                        float v = risk[((size_t)r * Bn + i) * Tn + lane];
                        float cc = v;
#pragma unroll
                        for (int o = 1; o < 64; o <<= 1) {
                            float u = __shfl_up(cc, o, 64);
                            if (lane >= o) cc += u;
                        }
                        S[lane][ls] = cc;     // stride-65: 2-way bank alias, free
                        int ti = tbS[ls];
                        float p = __shfl(v, ti, 64);
                        if (lane == 0 && rind[i * R + r]) {
                            int slot = r * 32 + ((k0 + ls) & 31);
                            atomicAdd(&llsumArr[slot], logf(p + EPS));
                            atomicAdd(&cntArr[slot], 1);
                        }
                    }
                }
                __syncthreads();
                // coalesced transposed write-out: 1024 threads = 16 rows x 64 cols
                int col = tid & 63, tr0 = tid >> 6;
                if (col < cnt) {
                    float* dst = cumTs + ((size_t)r * Tn) * Bn + k0;
#pragma unroll
                    for (int m = 0; m < 4; ++m) {
                        int t = m * 16 + tr0;
                        dst[(size_t)t * Bn + col] = S[t][col];
                    }
                }
                __syncthreads();
            } else {
#pragma unroll
                for (int s = 0; s < 4; ++s) {
                    int ls = s * 16 + w;
                    if (ls < cnt) {
                        int i  = idxS[ls];
                        int ti = tbS[ls];
                        float v = risk[((size_t)r * Bn + i) * Tn + lane];
                        v = (lane <= ti) ? v : 0.f;
#pragma unroll
                        for (int o = 32; o > 0; o >>= 1) v += __shfl_down(v, o, 64);
                        if (lane == 0) aCens[r * Bn + k0 + ls] = v;
                    }
                }
                __syncthreads();
            }
        }
    }
    gridbar(bar, 4);

    // ---- P4: rank. task b = r*128 + t*2 + half ----
    {
        int r    = b >> 7;
        int t    = (b >> 1) & 63;
        int half = b & 1;
        int ne = limE[t], nc = ncensA[t], cb = cbaseA[t];
        float s = 0.f;
        if (ne > 0 && nc > 0) {
            int e0 = tid * 4;
            const float* rowp = cumTs + ((size_t)(r * Tn + t)) * Bn;
            float4 c4 = *reinterpret_cast<const float4*>(rowp + e0);
            float c0 = (e0 + 0 < ne) ? c4.x * INV_SIGMA : INFINITY;
            float c1 = (e0 + 1 < ne) ? c4.y * INV_SIGMA : INFINITY;
            float c2 = (e0 + 2 < ne) ? c4.z * INV_SIGMA : INFINITY;
            float c3 = (e0 + 3 < ne) ? c4.w * INV_SIGMA : INFINITY;
            int lo = half ? (nc >> 1) : 0;
            int hi = half ? nc : (nc >> 1);
            const float* aC = aCens + r * Bn + cb;
            float s0 = 0.f, s1 = 0.f, s2 = 0.f, s3 = 0.f;
#pragma unroll 4
            for (int ci = lo; ci < hi; ++ci) {
                float a10 = aC[ci] * INV_SIGMA;   // wave-uniform scalar load
                s0 += __builtin_amdgcn_rcpf(1.f + __expf(c0 - a10));
                s1 += __builtin_amdgcn_rcpf(1.f + __expf(c1 - a10));
                s2 += __builtin_amdgcn_rcpf(1.f + __expf(c2 - a10));
                s3 += __builtin_amdgcn_rcpf(1.f + __expf(c3 - a10));
            }
            s = (s0 + s1) + (s2 + s3);
        }
#pragma unroll
        for (int o = 32; o > 0; o >>= 1) s += __shfl_down(s, o, 64);
        if (lane == 0) {
            int r2 = b >> 7;
            atomicAdd(&rlsumArr[r2 * 32 + ((b * 16 + w) & 31)], s);
        }
    }
    gridbar(bar, 5);

    // ---- P5: final ----
    if (b == 0 && tid < 64) {
        float lg = llsumArr[tid];
        float rl = rlsumArr[tid];
        int   cn = cntArr[tid];
#pragma unroll
        for (int o = 1; o <= 16; o <<= 1) {
            lg += __shfl_xor(lg, o, 64);
            rl += __shfl_xor(rl, o, 64);
            cn += __shfl_xor(cn, o, 64);
        }
        float lg1 = __shfl(lg, 32, 64);
        float rl1 = __shfl(rl, 32, 64);
        int   cn1 = __shfl(cn, 32, 64);
        if (tid == 0) {
            float ll0 = (cn  > 0) ? (-lg  / (float)cn ) : 0.f;
            float ll1 = (cn1 > 0) ? (-lg1 / (float)cn1) : 0.f;
            out[0] = 0.5f * (ll0 + ll1) + 0.5f * (rl + rl1);
        }
    }
}

extern "C" void kernel_launch(void* const* d_in, const int* in_sizes, int n_in,
                              void* d_out, int out_size, void* d_ws, size_t ws_size,
                              hipStream_t stream) {
    const float* risk = (const float*)d_in[0];
    const int* tb     = (const int*)d_in[1];
    const int* rind   = (const int*)d_in[2];
    const int* ev     = (const int*)d_in[3];

    // zero accumulators + barrier state + histogram bins (ints [0,336))
    hipMemsetAsync(d_ws, 0, 336 * 4, stream);
    k_fused<<<NB, NT, 0, stream>>>(risk, tb, rind, ev, (float*)d_out,
                                   (int*)d_ws);
}

// Round 8
// 158.173 us; speedup vs baseline: 1.6075x; 1.6075x over previous
//
#include <hip/hip_runtime.h>
#include <math.h>

// DeepHit loss, MI355X. R=2 risks, B=8192, T=64 bins.
// Ints/bools delivered as int32 (verified: absmax 0).
//
// SINGLE persistent kernel (256 blocks x 1024 threads, co-resident) with
// THREE device-scope grid barriers:
//   P0 prep   : block 0 only — LDS histogram + wave prefix + counting-sort
//               scatter (esort/csort) + publish limE/cbase/ncens.
//   P1 cum    : 512 tasks. Event tiles: 16 waves x 4 rows shuffle-scan ->
//               LDS tile -> coalesced transposed cumTs store + likelihood.
//               Censored tiles: masked row-sum -> aCens (censored-sorted).
//   P2 rank   : task b = (r, t, event-half). 4 events/thread in registers
//               (halves cover all 8192 slots — R7 only covered 4096!),
//               loop over bin-t censored with wave-uniform scalar a.
//   P3 final  : block 0 wave 0.
//
// R7 post-mortem: ACQUIRE-poll spin barrier = per-iteration L2 invalidate
// (buffer_inv) from 255 blocks -> chip-wide cache-invalidate storm, 205 us
// at 3.9% VALUBusy. Fixed: relaxed polls + single acquire fence on exit,
// monotonic counter (no reset race), s_sleep(16) between polls.

namespace {
constexpr int R  = 2;
constexpr int Bn = 8192;
constexpr int Tn = 64;
constexpr int NB = 256;
constexpr int NT = 1024;
constexpr float INV_SIGMA = 10.0f;   // 1/0.1
constexpr float EPS       = 1e-8f;
}

// ws layout (int32 offsets):
// 0    float llsumArr[64]   (zeroed each call)
// 64   int   cntArr[64]     (zeroed)
// 128  float rlsumArr[64]   (zeroed)
// 192  int   barCnt         (zeroed; monotonic)
// 256  int   limE[64]       (inclusive event prefix)
// 320  int   cbase[64]      (exclusive censored prefix)
// 384  int   ncens[64]
// 1024 int   esort[8192]
// 9216 int   csort[8192]
// 17408 float aCens[2*8192]
// 33792 float cumTs[2*64*8192]   (4 MB)

__device__ __forceinline__ void gridbar(int* cnt, int target) {
    __syncthreads();
    if (threadIdx.x == 0) {
        __threadfence();   // release: drain + write back our dirty lines
        __hip_atomic_fetch_add(cnt, 1, __ATOMIC_RELAXED,
                               __HIP_MEMORY_SCOPE_AGENT);
        while (__hip_atomic_load(cnt, __ATOMIC_RELAXED,
                                 __HIP_MEMORY_SCOPE_AGENT) < target) {
            __builtin_amdgcn_s_sleep(16);   // ~1024 cy between polls
        }
        __threadfence();   // acquire ONCE after exit (single invalidate)
    }
    __syncthreads();
}

__global__ void __launch_bounds__(NT)
k_fused(const float* __restrict__ risk, const int* __restrict__ tb,
        const int* __restrict__ rind, const int* __restrict__ ev,
        float* __restrict__ out, int* __restrict__ wsI) {
    float* llsumArr = (float*)(wsI + 0);
    int*   cntArr   = wsI + 64;
    float* rlsumArr = (float*)(wsI + 128);
    int*   barCnt   = wsI + 192;
    int*   limE     = wsI + 256;
    int*   cbaseA   = wsI + 320;
    int*   ncensA   = wsI + 384;
    int*   esort    = wsI + 1024;
    int*   csort    = wsI + 9216;
    float* aCens    = (float*)(wsI + 17408);
    float* cumTs    = (float*)(wsI + 33792);

    const int b    = blockIdx.x;
    const int tid  = threadIdx.x;
    const int lane = tid & 63;
    const int w    = tid >> 6;

    __shared__ float S[Tn][Tn + 1];
    __shared__ int idxS[Tn], tbS[Tn];
    __shared__ int hE[Tn], hC[Tn], wE[Tn], wC[Tn];

    // ---- P0: prep, block 0 only (hist + prefix + scatter) ----
    if (b == 0) {
        if (tid < Tn) { hE[tid] = 0; hC[tid] = 0; }
        __syncthreads();
#pragma unroll
        for (int k = 0; k < 8; ++k) {
            int j = tid + k * NT;
            int t = tb[j];
            if (ev[j]) atomicAdd(&hE[t], 1);
            else       atomicAdd(&hC[t], 1);
        }
        __syncthreads();
        if (tid < 64) {
            int eC = hE[tid], cC = hC[tid];
            int se = eC, sc = cC;
#pragma unroll
            for (int o = 1; o < 64; o <<= 1) {
                int ue = __shfl_up(se, o, 64);
                int uc = __shfl_up(sc, o, 64);
                if (lane >= o) { se += ue; sc += uc; }
            }
            limE[tid]   = se;
            cbaseA[tid] = sc - cC;
            ncensA[tid] = cC;
            wE[tid] = se - eC;     // LDS working offsets for scatter
            wC[tid] = sc - cC;
        }
        __syncthreads();
#pragma unroll
        for (int k = 0; k < 8; ++k) {
            int j = tid + k * NT;
            int t = tb[j];
            if (ev[j]) { int p = atomicAdd(&wE[t], 1); esort[p] = j; }
            else       { int p = atomicAdd(&wC[t], 1); csort[p] = j; }
        }
    }
    gridbar(barCnt, NB);

    // ---- P1: cum tiles (512 tasks; each block does c = b, then b+256) ----
    int nE = limE[Tn - 1];
    int nC = Bn - nE;
    for (int c = b; c < 512; c += NB) {
        bool isEvent = (c < 256);
        int r  = (c >> 7) & 1;
        int k0 = (c & 127) * 64;
        int tot = isEvent ? nE : nC;
        if (k0 < tot) {                       // block-uniform condition
            int cnt = min(64, tot - k0);
            if (tid < cnt) {
                int i = isEvent ? esort[k0 + tid] : csort[k0 + tid];
                idxS[tid] = i;
                tbS[tid]  = tb[i];
            }
            __syncthreads();
            if (isEvent) {
#pragma unroll
                for (int s = 0; s < 4; ++s) {
                    int ls = s * 16 + w;      // wave-uniform row pick
                    if (ls < cnt) {
                        int i = idxS[ls];
                        float v = risk[((size_t)r * Bn + i) * Tn + lane];
                        float cc = v;
#pragma unroll
                        for (int o = 1; o < 64; o <<= 1) {
                            float u = __shfl_up(cc, o, 64);
                            if (lane >= o) cc += u;
                        }
                        S[lane][ls] = cc;     // stride-65: 2-way alias, free
                        int ti = tbS[ls];
                        float p = __shfl(v, ti, 64);
                        if (lane == 0 && rind[i * R + r]) {
                            int slot = r * 32 + ((k0 + ls) & 31);
                            atomicAdd(&llsumArr[slot], logf(p + EPS));
                            atomicAdd(&cntArr[slot], 1);
                        }
                    }
                }
                __syncthreads();
                // coalesced transposed write: 1024 thr = 16 rows x 64 cols
                int col = tid & 63, tr0 = tid >> 6;
                if (col < cnt) {
                    float* dst = cumTs + ((size_t)r * Tn) * Bn + k0;
#pragma unroll
                    for (int m = 0; m < 4; ++m) {
                        int t = m * 16 + tr0;
                        dst[(size_t)t * Bn + col] = S[t][col];
                    }
                }
                __syncthreads();
            } else {
#pragma unroll
                for (int s = 0; s < 4; ++s) {
                    int ls = s * 16 + w;
                    if (ls < cnt) {
                        int i  = idxS[ls];
                        int ti = tbS[ls];
                        float v = risk[((size_t)r * Bn + i) * Tn + lane];
                        v = (lane <= ti) ? v : 0.f;
#pragma unroll
                        for (int o = 32; o > 0; o >>= 1) v += __shfl_down(v, o, 64);
                        if (lane == 0) aCens[r * Bn + k0 + ls] = v;
                    }
                }
                __syncthreads();
            }
        }
    }
    gridbar(barCnt, 2 * NB);

    // ---- P2: rank. task b = r*128 + t*2 + eventHalf ----
    {
        int r    = b >> 7;
        int t    = (b >> 1) & 63;
        int half = b & 1;
        int ne = limE[t], nc = ncensA[t], cb = cbaseA[t];
        int e0 = half * 4096 + tid * 4;       // halves cover all 8192 slots
        float s = 0.f;
        if (nc > 0 && half * 4096 < ne) {     // block-uniform skip
            const float* rowp = cumTs + ((size_t)(r * Tn + t)) * Bn;
            float4 c4 = *reinterpret_cast<const float4*>(rowp + e0);
            float c0 = (e0 + 0 < ne) ? c4.x * INV_SIGMA : INFINITY;
            float c1 = (e0 + 1 < ne) ? c4.y * INV_SIGMA : INFINITY;
            float c2 = (e0 + 2 < ne) ? c4.z * INV_SIGMA : INFINITY;
            float c3 = (e0 + 3 < ne) ? c4.w * INV_SIGMA : INFINITY;
            const float* aC = aCens + r * Bn + cb;
            float s0 = 0.f, s1 = 0.f, s2 = 0.f, s3 = 0.f;
#pragma unroll 4
            for (int ci = 0; ci < nc; ++ci) {
                float a10 = aC[ci] * INV_SIGMA;   // wave-uniform scalar load
                s0 += __builtin_amdgcn_rcpf(1.f + __expf(c0 - a10));
                s1 += __builtin_amdgcn_rcpf(1.f + __expf(c1 - a10));
                s2 += __builtin_amdgcn_rcpf(1.f + __expf(c2 - a10));
                s3 += __builtin_amdgcn_rcpf(1.f + __expf(c3 - a10));
            }
            s = (s0 + s1) + (s2 + s3);
        }
#pragma unroll
        for (int o = 32; o > 0; o >>= 1) s += __shfl_down(s, o, 64);
        if (lane == 0) {
            atomicAdd(&rlsumArr[(b >> 7) * 32 + ((b * 16 + w) & 31)], s);
        }
    }
    gridbar(barCnt, 3 * NB);

    // ---- P3: final ----
    if (b == 0 && tid < 64) {
        float lg = llsumArr[tid];
        float rl = rlsumArr[tid];
        int   cn = cntArr[tid];
#pragma unroll
        for (int o = 1; o <= 16; o <<= 1) {
            lg += __shfl_xor(lg, o, 64);
            rl += __shfl_xor(rl, o, 64);
            cn += __shfl_xor(cn, o, 64);
        }
        float lg1 = __shfl(lg, 32, 64);
        float rl1 = __shfl(rl, 32, 64);
        int   cn1 = __shfl(cn, 32, 64);
        if (tid == 0) {
            float ll0 = (cn  > 0) ? (-lg  / (float)cn ) : 0.f;
            float ll1 = (cn1 > 0) ? (-lg1 / (float)cn1) : 0.f;
            out[0] = 0.5f * (ll0 + ll1) + 0.5f * (rl + rl1);
        }
    }
}

extern "C" void kernel_launch(void* const* d_in, const int* in_sizes, int n_in,
                              void* d_out, int out_size, void* d_ws, size_t ws_size,
                              hipStream_t stream) {
    const float* risk = (const float*)d_in[0];
    const int* tb     = (const int*)d_in[1];
    const int* rind   = (const int*)d_in[2];
    const int* ev     = (const int*)d_in[3];

    // zero accumulators + barrier counter (ints [0,256))
    hipMemsetAsync(d_ws, 0, 1024, stream);
    k_fused<<<NB, NT, 0, stream>>>(risk, tb, rind, ev, (float*)d_out,
                                   (int*)d_ws);
}

// Round 10
// 133.517 us; speedup vs baseline: 1.9043x; 1.1847x over previous
//
#include <hip/hip_runtime.h>
#include <math.h>

// DeepHit loss, MI355X. R=2 risks, B=8192, T=64 bins.
// Ints/bools delivered as int32 (verified: absmax 0).
//
// SINGLE persistent kernel (256 blocks x 1024 threads) with THREE
// fence-free grid barriers. All cross-phase data moves through
// agent-scope RELAXED atomics (sc1-flagged, cross-XCD coherent point ops)
// so NO full-L2 writeback/invalidate is ever issued.
//
//   P0 prep   : block 0 — LDS histogram + wave prefix + counting-sort.
//   P1 cum    : 512 tasks. Event tiles: 16 waves x 4 rows shuffle-scan ->
//               LDS tile -> coalesced transposed cumTs store (atomic st)
//               + likelihood. Censored tiles: masked row-sum -> aCens.
//   P2 rank   : task b = (r, t, event-half); 4 events/thread in registers,
//               bin's censored 'a' values staged into LDS, inner loop
//               is pure VALU/trans.
//   P3 final  : block 0 wave 0 (atomic loads of accumulators).
//
// R7: ACQUIRE-poll spin = per-poll L2 invalidate storm (205 us).
// R8: one release-wbl2 + acquire-inv per block per barrier (256 x 3
//     full-L2 tag scans) left kernel at 104 us, VALUBusy 7%.
// R9: fence-free version — infra failure (container died twice), never ran.
//     Design re-audited for deadlock (co-residency, barrier reachability,
//     poll progress proven in R8): none found. Resubmitted unchanged.

namespace {
constexpr int R  = 2;
constexpr int Bn = 8192;
constexpr int Tn = 64;
constexpr int NB = 256;
constexpr int NT = 1024;
constexpr float INV_SIGMA = 10.0f;   // 1/0.1
constexpr float EPS       = 1e-8f;
}

#define AL(p)    __hip_atomic_load((p), __ATOMIC_RELAXED, __HIP_MEMORY_SCOPE_AGENT)
#define AS(p, v) __hip_atomic_store((p), (v), __ATOMIC_RELAXED, __HIP_MEMORY_SCOPE_AGENT)

// ws layout (int32 offsets):
// 0    float llsumArr[64]   (zeroed each call)
// 64   int   cntArr[64]     (zeroed)
// 128  float rlsumArr[64]   (zeroed)
// 192  int   barCnt         (zeroed; monotonic)
// 256  int   limE[64]       (inclusive event prefix)
// 320  int   cbase[64]      (exclusive censored prefix)
// 384  int   ncens[64]
// 1024 int   esort[8192]
// 9216 int   csort[8192]
// 17408 float aCens[2*8192]
// 33792 float cumTs[2*64*8192]   (4 MB)

__device__ __forceinline__ void gridbar(int* cnt, int target) {
    __syncthreads();   // each wave drains vmcnt before s_barrier (compiler-emitted)
    if (threadIdx.x == 0) {
        __hip_atomic_fetch_add(cnt, 1, __ATOMIC_RELAXED,
                               __HIP_MEMORY_SCOPE_AGENT);
        while (AL(cnt) < target) __builtin_amdgcn_s_sleep(8);
    }
    __syncthreads();
}

__global__ void __launch_bounds__(NT)
k_fused(const float* __restrict__ risk, const int* __restrict__ tb,
        const int* __restrict__ rind, const int* __restrict__ ev,
        float* __restrict__ out, int* __restrict__ wsI) {
    float* llsumArr = (float*)(wsI + 0);
    int*   cntArr   = wsI + 64;
    float* rlsumArr = (float*)(wsI + 128);
    int*   barCnt   = wsI + 192;
    int*   limE     = wsI + 256;
    int*   cbaseA   = wsI + 320;
    int*   ncensA   = wsI + 384;
    int*   esort    = wsI + 1024;
    int*   csort    = wsI + 9216;
    float* aCens    = (float*)(wsI + 17408);
    float* cumTs    = (float*)(wsI + 33792);

    const int b    = blockIdx.x;
    const int tid  = threadIdx.x;
    const int lane = tid & 63;
    const int w    = tid >> 6;

    __shared__ float S[Tn][Tn + 1];      // P1 tile; P2 reuses as aS
    __shared__ int idxS[Tn], tbS[Tn];
    __shared__ int hE[Tn], hC[Tn], wE[Tn], wC[Tn];
    float* aS = &S[0][0];

    // ---- P0: prep, block 0 only (hist + prefix + scatter) ----
    if (b == 0) {
        if (tid < Tn) { hE[tid] = 0; hC[tid] = 0; }
        __syncthreads();
#pragma unroll
        for (int k = 0; k < 8; ++k) {
            int j = tid + k * NT;
            int t = tb[j];
            if (ev[j]) atomicAdd(&hE[t], 1);
            else       atomicAdd(&hC[t], 1);
        }
        __syncthreads();
        if (tid < 64) {
            int eC = hE[tid], cC = hC[tid];
            int se = eC, sc = cC;
#pragma unroll
            for (int o = 1; o < 64; o <<= 1) {
                int ue = __shfl_up(se, o, 64);
                int uc = __shfl_up(sc, o, 64);
                if (lane >= o) { se += ue; sc += uc; }
            }
            AS(&limE[tid], se);
            AS(&cbaseA[tid], sc - cC);
            AS(&ncensA[tid], cC);
            wE[tid] = se - eC;     // LDS working offsets for scatter
            wC[tid] = sc - cC;
        }
        __syncthreads();
#pragma unroll
        for (int k = 0; k < 8; ++k) {
            int j = tid + k * NT;
            int t = tb[j];
            if (ev[j]) { int p = atomicAdd(&wE[t], 1); AS(&esort[p], j); }
            else       { int p = atomicAdd(&wC[t], 1); AS(&csort[p], j); }
        }
    }
    gridbar(barCnt, NB);

    // ---- P1: cum tiles (512 tasks; each block does c = b, then b+256) ----
    int nE = AL(&limE[Tn - 1]);
    int nC = Bn - nE;
    for (int c = b; c < 512; c += NB) {
        bool isEvent = (c < 256);
        int r  = (c >> 7) & 1;
        int k0 = (c & 127) * 64;
        int tot = isEvent ? nE : nC;
        if (k0 < tot) {                       // block-uniform condition
            int cnt = min(64, tot - k0);
            if (tid < cnt) {
                int i = isEvent ? AL(&esort[k0 + tid]) : AL(&csort[k0 + tid]);
                idxS[tid] = i;
                tbS[tid]  = tb[i];
            }
            __syncthreads();
            if (isEvent) {
#pragma unroll
                for (int s = 0; s < 4; ++s) {
                    int ls = s * 16 + w;      // wave-uniform row pick
                    if (ls < cnt) {
                        int i = idxS[ls];
                        float v = risk[((size_t)r * Bn + i) * Tn + lane];
                        float cc = v;
#pragma unroll
                        for (int o = 1; o < 64; o <<= 1) {
                            float u = __shfl_up(cc, o, 64);
                            if (lane >= o) cc += u;
                        }
                        S[lane][ls] = cc;     // stride-65: 2-way alias, free
                        int ti = tbS[ls];
                        float p = __shfl(v, ti, 64);
                        if (lane == 0 && rind[i * R + r]) {
                            int slot = r * 32 + ((k0 + ls) & 31);
                            atomicAdd(&llsumArr[slot], logf(p + EPS));
                            atomicAdd(&cntArr[slot], 1);
                        }
                    }
                }
                __syncthreads();
                // coalesced transposed write: 1024 thr = 16 rows x 64 cols
                int col = tid & 63, tr0 = tid >> 6;
                if (col < cnt) {
                    float* dst = cumTs + ((size_t)r * Tn) * Bn + k0;
#pragma unroll
                    for (int m = 0; m < 4; ++m) {
                        int t = m * 16 + tr0;
                        AS(&dst[(size_t)t * Bn + col], S[t][col]);
                    }
                }
                __syncthreads();
            } else {
#pragma unroll
                for (int s = 0; s < 4; ++s) {
                    int ls = s * 16 + w;
                    if (ls < cnt) {
                        int i  = idxS[ls];
                        int ti = tbS[ls];
                        float v = risk[((size_t)r * Bn + i) * Tn + lane];
                        v = (lane <= ti) ? v : 0.f;
#pragma unroll
                        for (int o = 32; o > 0; o >>= 1) v += __shfl_down(v, o, 64);
                        if (lane == 0) AS(&aCens[r * Bn + k0 + ls], v);
                    }
                }
                __syncthreads();
            }
        }
    }
    gridbar(barCnt, 2 * NB);

    // ---- P2: rank. task b = r*128 + t*2 + eventHalf ----
    {
        int r    = b >> 7;
        int t    = (b >> 1) & 63;
        int half = b & 1;
        int ne = AL(&limE[t]);
        int nc = AL(&ncensA[t]);
        int cb = AL(&cbaseA[t]);
        int e0 = half * 4096 + tid * 4;       // halves cover all 8192 slots
        float s = 0.f;
        if (nc > 0 && half * 4096 < ne) {     // block-uniform skip
            float* rowp = cumTs + ((size_t)(r * Tn + t)) * Bn;
            float x0 = AL(&rowp[e0 + 0]), x1 = AL(&rowp[e0 + 1]);
            float x2 = AL(&rowp[e0 + 2]), x3 = AL(&rowp[e0 + 3]);
            float c0 = (e0 + 0 < ne) ? x0 * INV_SIGMA : INFINITY;
            float c1 = (e0 + 1 < ne) ? x1 * INV_SIGMA : INFINITY;
            float c2 = (e0 + 2 < ne) ? x2 * INV_SIGMA : INFINITY;
            float c3 = (e0 + 3 < ne) ? x3 * INV_SIGMA : INFINITY;
            float s0 = 0.f, s1 = 0.f, s2 = 0.f, s3 = 0.f;
            for (int cc = 0; cc < nc; cc += NT) {
                int chunk = min(NT, nc - cc);
                if (cc) __syncthreads();               // aS reuse hazard
                if (tid < chunk) aS[tid] = AL(&aCens[r * Bn + cb + cc + tid]);
                __syncthreads();
#pragma unroll 4
                for (int ci = 0; ci < chunk; ++ci) {
                    float a10 = aS[ci] * INV_SIGMA;    // LDS broadcast
                    s0 += __builtin_amdgcn_rcpf(1.f + __expf(c0 - a10));
                    s1 += __builtin_amdgcn_rcpf(1.f + __expf(c1 - a10));
                    s2 += __builtin_amdgcn_rcpf(1.f + __expf(c2 - a10));
                    s3 += __builtin_amdgcn_rcpf(1.f + __expf(c3 - a10));
                }
            }
            s = (s0 + s1) + (s2 + s3);
        }
#pragma unroll
        for (int o = 32; o > 0; o >>= 1) s += __shfl_down(s, o, 64);
        if (lane == 0) {
            atomicAdd(&rlsumArr[(b >> 7) * 32 + ((b * 16 + w) & 31)], s);
        }
    }
    gridbar(barCnt, 3 * NB);

    // ---- P3: final ----
    if (b == 0 && tid < 64) {
        float lg = AL(&llsumArr[tid]);
        float rl = AL(&rlsumArr[tid]);
        int   cn = AL(&cntArr[tid]);
#pragma unroll
        for (int o = 1; o <= 16; o <<= 1) {
            lg += __shfl_xor(lg, o, 64);
            rl += __shfl_xor(rl, o, 64);
            cn += __shfl_xor(cn, o, 64);
        }
        float lg1 = __shfl(lg, 32, 64);
        float rl1 = __shfl(rl, 32, 64);
        int   cn1 = __shfl(cn, 32, 64);
        if (tid == 0) {
            float ll0 = (cn  > 0) ? (-lg  / (float)cn ) : 0.f;
            float ll1 = (cn1 > 0) ? (-lg1 / (float)cn1) : 0.f;
            out[0] = 0.5f * (ll0 + ll1) + 0.5f * (rl + rl1);
        }
    }
}

extern "C" void kernel_launch(void* const* d_in, const int* in_sizes, int n_in,
                              void* d_out, int out_size, void* d_ws, size_t ws_size,
                              hipStream_t stream) {
    const float* risk = (const float*)d_in[0];
    const int* tb     = (const int*)d_in[1];
    const int* rind   = (const int*)d_in[2];
    const int* ev     = (const int*)d_in[3];

    // zero accumulators + barrier counter (ints [0,256))
    hipMemsetAsync(d_ws, 0, 1024, stream);
    k_fused<<<NB, NT, 0, stream>>>(risk, tb, rind, ev, (float*)d_out,
                                   (int*)d_ws);
}